// Round 12
// baseline (402.697 us; speedup 1.0000x reference)
//
#include <hip/hip_runtime.h>
#include <hip/hip_bf16.h>

#define N_NODES 30000
#define N_EDGES 120000
#define NGRAPH  512
#define N2      15000
#define N3      7500
#define NC      10

#define TSN   4                 // src pooled-nodes per tile in k4
#define NTS   (N2 / TSN)        // 3750
#define EC4   64                // edge chunk, k4
#define NB1   32                // original nodes per block, k1
#define NBLK1 ((N_NODES + NB1 - 1) / NB1)   // 938
#define EC1   256               // edge chunk, k1
#define NDEGB ((N_EDGES + 255) / 256)       // 469

// scan chunking: deg1(30000), degN(15000), deg2(15000)
#define SC_C1 118
#define SC_CN 59
#define SC_C2 59
#define SC_CT (SC_C1 + SC_CN + SC_C2)   // 236

typedef __hip_bfloat16 bf16;

__device__ __forceinline__ float lo(const float* p, int i) { return p[i]; }
__device__ __forceinline__ float lo(const bf16* p, int i) { return __bfloat162float(p[i]); }
__device__ __forceinline__ void sto(float* p, int i, float v) { p[i] = v; }
__device__ __forceinline__ void sto(bf16* p, int i, float v) { p[i] = __float2bfloat16(v); }
__device__ __forceinline__ float elu(float x) { return x > 0.f ? x : expm1f(x); }

// ---------------- workspace layout (4-byte units) ----------------
// zero region (memset each call):
#define MV_OFF    0         // maxv (uint bits): 1
#define GS_OFF    1         // gsum: 512*64 = 32768
#define GC_OFF    32769     // gcnt: 512
#define DEG1_OFF  33281     // in-degree per node (int): 30000
#define DEG2_OFF  63281     // valid in-degree per pooled node (int): 15000
#define DEGN_OFF  78281     // valid out-degree per pooled SRC node (int): 15000
#define ZERO_FLOATS 93281
// non-zero region:
#define OFF1_OFF  93281     // conv1 CSR offsets (int): 30001
#define CUR1_OFF  123282    // 30000
#define OFF2_OFF  153282    // conv2 dest CSR offsets (int): 15001
#define CUR2_OFF  168283    // 15000
#define OFFN_OFF  183283    // conv2 src-node CSR offsets (int): 15001
#define CURN_OFF  198284    // 15000
#define BSUM_OFF  213284    // scan chunk sums (int): 236
#define ES1_OFF   213520    // conv1 dest-sorted edge ids (int): 120000
#define ESS_OFF   333520    // conv2 src-node-sorted edge ids (int): 120000
#define DPOS_OFF  453520    // edge -> dest-sorted row (int): 120000
#define X2_OFF    573520    // x2: N2*32 = 480000
#define P2_OFF    1053520   // pos2: N2*2 = 30000
#define CT_OFF    1083520   // cart: E*2 = 240000
#define MSG_OFF   1323520   // message buffer: E*64 = 7680000
#define FLAG_OFF  9003520   // dtype flag (int)
// total = 9003521 floats ~= 36 MB

// ---------------- shared-memory layouts (dynamic, shared across dtype branches)
struct K1Smem {
  float srow[NB1][28];
  float axl[EC1], ayl[EC1], xsl[EC1];
  float w1a[50];
  float b1a[25];
  float b1b[32];
  float r1[32];
  float bs1[32];
  float hbuf[NB1][33];
  int offl[NB1 + 1];
};  // ~12 KB

struct K4Smem {
  float Y[TSN][26][64];   // 26.6 KB; writes+reads conflict-free (proven r4/r7)
  __align__(16) float tl[EC4][32];  // 8 KB; rows b128-able; t[25]=1, 26..31=0
  __align__(16) float xl[TSN][32];  // rows 128B -> b128 broadcast reads
  float w2a[50];
  float b2a[25];
  float axl[EC4], ayl[EC4];
  int dpl[EC4], nll[EC4];
};  // ~37 KB -> 4 blocks/CU

struct K5Smem {
  float r2l[2048];
  float b2l[64];
  float hl[4][64];
};  // ~9.5 KB

// ---------------- degree histograms + dtype detect (fused; dtype-free)
__global__ __launch_bounds__(256) void kc_deg(
    const int* __restrict__ ei, const void* x, const void* ea, int* __restrict__ flag,
    int* __restrict__ deg1, int* __restrict__ deg2, int* __restrict__ degN) {
  if (blockIdx.x == NDEGB) {
    const bf16* xb = (const bf16*)x;
    const bf16* eb = (const bf16*)ea;
    int tid = threadIdx.x;
    float a = __bfloat162float(xb[tid]);
    float b = __bfloat162float(eb[tid]);
    int bad = (!(fabsf(a) < 1e3f)) || (!(fabsf(b) < 1e3f));
    unsigned long long m = __ballot(bad);
    __shared__ int anyb[4];
    int w = tid >> 6;
    if ((tid & 63) == 0) anyb[w] = (m != 0ULL) ? 1 : 0;
    __syncthreads();
    if (tid == 0) flag[0] = (anyb[0] | anyb[1] | anyb[2] | anyb[3]);
    return;
  }
  int e = blockIdx.x * 256 + threadIdx.x;
  if (e >= N_EDGES) return;
  int row = ei[e], col = ei[N_EDGES + e];
  atomicAdd(deg1 + col, 1);
  int r2 = row >> 1, c2 = col >> 1;
  if (r2 != c2) {
    atomicAdd(deg2 + c2, 1);
    atomicAdd(degN + r2, 1);
  }
}

// ---------------- hierarchical exclusive scan over the three deg arrays
__global__ __launch_bounds__(256) void ks_scanA(
    const int* __restrict__ deg1, const int* __restrict__ degN, const int* __restrict__ deg2,
    int* __restrict__ off1, int* __restrict__ offN, int* __restrict__ off2,
    int* __restrict__ bsum) {
  __shared__ int buf[256];
  int c = blockIdx.x, tid = threadIdx.x;
  const int* deg; int* off; int n, local;
  if (c < SC_C1)              { deg = deg1; off = off1; n = 30000; local = c; }
  else if (c < SC_C1 + SC_CN) { deg = degN; off = offN; n = 15000; local = c - SC_C1; }
  else                        { deg = deg2; off = off2; n = 15000; local = c - SC_C1 - SC_CN; }
  int i = local * 256 + tid;
  int v = (i < n) ? deg[i] : 0;
  buf[tid] = v;
  __syncthreads();
  for (int s = 1; s < 256; s <<= 1) {
    int t = (tid >= s) ? buf[tid - s] : 0;
    __syncthreads();
    buf[tid] += t;
    __syncthreads();
  }
  if (i <= n) off[i] = buf[tid] - v;
  if (tid == 255) bsum[c] = buf[255];
}

__global__ __launch_bounds__(256) void ks_scanB(int* __restrict__ bsum) {
  __shared__ int buf[256];
  int a = blockIdx.x, tid = threadIdx.x;
  int nc, cb;
  if (a == 0)      { nc = SC_C1; cb = 0; }
  else if (a == 1) { nc = SC_CN; cb = SC_C1; }
  else             { nc = SC_C2; cb = SC_C1 + SC_CN; }
  int v = (tid < nc) ? bsum[cb + tid] : 0;
  buf[tid] = v;
  __syncthreads();
  for (int s = 1; s < 256; s <<= 1) {
    int t = (tid >= s) ? buf[tid - s] : 0;
    __syncthreads();
    buf[tid] += t;
    __syncthreads();
  }
  if (tid < nc) bsum[cb + tid] = buf[tid] - v;
}

__global__ __launch_bounds__(256) void ks_scanC(
    int* __restrict__ off1, int* __restrict__ offN, int* __restrict__ off2,
    int* __restrict__ cur1, int* __restrict__ curN, int* __restrict__ cur2,
    const int* __restrict__ bsum) {
  int c = blockIdx.x, tid = threadIdx.x;
  int* off; int* cur; int n, local;
  if (c < SC_C1)              { off = off1; cur = cur1; n = 30000; local = c; }
  else if (c < SC_C1 + SC_CN) { off = offN; cur = curN; n = 15000; local = c - SC_C1; }
  else                        { off = off2; cur = cur2; n = 15000; local = c - SC_C1 - SC_CN; }
  int add = bsum[c];
  int i = local * 256 + tid;
  if (i <= n) off[i] += add;
  if (i < n) cur[i] = off[i];
}

// ---------------- edge placement into CSR lists (dtype-free)
__global__ __launch_bounds__(256) void kc_place(const int* __restrict__ ei,
                                                int* __restrict__ cur1, int* __restrict__ es1,
                                                int* __restrict__ cur2, int* __restrict__ dpos,
                                                int* __restrict__ curN, int* __restrict__ ess) {
  int e = blockIdx.x * 256 + threadIdx.x;
  if (e >= N_EDGES) return;
  int row = ei[e], col = ei[N_EDGES + e];
  int p = atomicAdd(cur1 + col, 1);
  es1[p] = e;
  int r2 = row >> 1, c2 = col >> 1;
  if (r2 != c2) {
    int q = atomicAdd(cur2 + c2, 1);
    dpos[e] = q;
    int u = atomicAdd(curN + r2, 1);   // src-NODE grouped -> nl runs are contiguous
    ess[u] = e;
  }
}

// ---------------- conv1 v3: dest-side S factorization (f_in=1 -> S is 26 floats/node)
template <typename T>
__device__ void k1_impl(K1Smem& S,
    const T* __restrict__ x, const T* __restrict__ ea, const T* __restrict__ pos,
    const int* __restrict__ ei,
    const T* __restrict__ w1a, const T* __restrict__ b1a,
    const T* __restrict__ w1b, const T* __restrict__ b1b,
    const T* __restrict__ root1, const T* __restrict__ bias1,
    const int* __restrict__ off1, const int* __restrict__ es1,
    float* __restrict__ x2, float* __restrict__ pos2) {
  int tid = threadIdx.x, t = blockIdx.x;
  int n0 = t * NB1;
  for (int j = tid; j < 50; j += 256) S.w1a[j] = lo(w1a, j);
  for (int j = tid; j < 25; j += 256) S.b1a[j] = lo(b1a, j);
  if (tid < 32) {
    S.b1b[tid] = lo(b1b, tid);
    S.r1[tid] = lo(root1, tid);
    S.bs1[tid] = lo(bias1, tid);
  }
  if (tid <= NB1) {
    int n = n0 + tid; if (n > N_NODES) n = N_NODES;
    S.offl[tid] = off1[n];
  }
  int half = tid >> 5, lk = tid & 31;
  float wreg[28];
#pragma unroll
  for (int k = 0; k < 25; ++k) wreg[k] = lo(w1b, k * 32 + lk);
  wreg[26] = 0.f; wreg[27] = 0.f;
  __syncthreads();
  wreg[25] = S.b1b[lk];
  float wa0 = 0.f, wa1 = 0.f, wb = 0.f;
  if (lk < 25) { wa0 = S.w1a[lk]; wa1 = S.w1a[25 + lk]; wb = S.b1a[lk]; }
  int jbeg = S.offl[0], jend = S.offl[NB1];
  int base = half * 4;
  float s0 = 0.f, s1 = 0.f, s2 = 0.f, s3 = 0.f;
  for (int jb = jbeg; jb < jend; jb += EC1) {
    int ecnt = jend - jb; if (ecnt > EC1) ecnt = EC1;
    __syncthreads();
    if (tid < ecnt) {
      int e = es1[jb + tid];
      S.axl[tid] = lo(ea, 2 * e);
      S.ayl[tid] = lo(ea, 2 * e + 1);
      S.xsl[tid] = lo(x, ei[e]);
    }
    __syncthreads();
    int je = jb + ecnt;
#define K1ACC(i, sacc) { \
    int lj = S.offl[base + i]; if (lj < jb) lj = jb; \
    int hj = S.offl[base + i + 1]; if (hj > je) hj = je; \
    for (int j = lj; j < hj; ++j) { \
      int sj = j - jb; \
      float tk = (lk < 25) ? fmaxf(S.axl[sj] * wa0 + S.ayl[sj] * wa1 + wb, 0.f) : 1.f; \
      sacc += S.xsl[sj] * tk; } }
    K1ACC(0, s0) K1ACC(1, s1) K1ACC(2, s2) K1ACC(3, s3)
#undef K1ACC
  }
  if (lk < 26) {
    S.srow[base][lk] = s0; S.srow[base + 1][lk] = s1;
    S.srow[base + 2][lk] = s2; S.srow[base + 3][lk] = s3;
  } else if (lk < 28) {
    S.srow[base][lk] = 0.f; S.srow[base + 1][lk] = 0.f;
    S.srow[base + 2][lk] = 0.f; S.srow[base + 3][lk] = 0.f;
  }
#pragma unroll
  for (int i = 0; i < 4; ++i) {
    int nl = base + i, n = n0 + nl;
    if (n < N_NODES) {
      const float4* sq = (const float4*)S.srow[nl];
      float a0 = 0.f, a1 = 0.f, a2 = 0.f, a3 = 0.f;
#pragma unroll
      for (int q = 0; q < 7; ++q) {
        float4 sv = sq[q];
        a0 += sv.x * wreg[4 * q];     a1 += sv.y * wreg[4 * q + 1];
        a2 += sv.z * wreg[4 * q + 2]; a3 += sv.w * wreg[4 * q + 3];
      }
      float c = (float)(S.offl[nl + 1] - S.offl[nl]);
      c = fmaxf(c, 1.f);
      S.hbuf[nl][lk] = elu(((a0 + a1) + (a2 + a3)) / c + lo(x, n) * S.r1[lk] + S.bs1[lk]);
    }
  }
  __syncthreads();
  for (int idx = tid; idx < (NB1 / 2) * 32; idx += 256) {
    int pl = idx >> 5, oo = idx & 31;
    int m = t * (NB1 / 2) + pl;
    if (m < N2)
      x2[m * 32 + oo] = fmaxf(S.hbuf[2 * pl][oo], S.hbuf[2 * pl + 1][oo]);
  }
  if (tid < NB1) {
    int pl = tid >> 1, c = tid & 1;
    int m = t * (NB1 / 2) + pl;
    if (m < N2)
      pos2[m * 2 + c] = 0.5f * (lo(pos, (2 * m) * 2 + c) + lo(pos, (2 * m + 1) * 2 + c));
  }
}

__global__ __launch_bounds__(256, 4) void k1_both(
    const int* __restrict__ flag,
    const void* x, const void* ea, const void* pos, const int* ei,
    const void* w1a, const void* b1a, const void* w1b, const void* b1b,
    const void* root1, const void* bias1,
    const int* off1, const int* es1, float* x2, float* pos2) {
  extern __shared__ char sm1[];
  K1Smem& S = *reinterpret_cast<K1Smem*>(sm1);
  if (flag[0] == 1)
    k1_impl<float>(S, (const float*)x, (const float*)ea, (const float*)pos, ei,
                   (const float*)w1a, (const float*)b1a, (const float*)w1b, (const float*)b1b,
                   (const float*)root1, (const float*)bias1, off1, es1, x2, pos2);
  else
    k1_impl<bf16>(S, (const bf16*)x, (const bf16*)ea, (const bf16*)pos, ei,
                  (const bf16*)w1a, (const bf16*)b1a, (const bf16*)w1b, (const bf16*)b1b,
                  (const bf16*)root1, (const bf16*)bias1, off1, es1, x2, pos2);
}

// ---------------- cart + global abs-max (fp32 intermediates only)
__global__ __launch_bounds__(256) void k3_cart(
    const int* __restrict__ ei, const float* __restrict__ pos2,
    float* __restrict__ cart, unsigned int* __restrict__ maxv) {
  int e = blockIdx.x * 256 + threadIdx.x;
  float m = 0.f;
  if (e < N_EDGES) {
    int r2 = ei[e] >> 1, c2 = ei[N_EDGES + e] >> 1;
    float cx = 0.f, cy = 0.f;
    if (r2 != c2) {
      cx = pos2[2 * c2] - pos2[2 * r2];
      cy = pos2[2 * c2 + 1] - pos2[2 * r2 + 1];
    }
    cart[2 * e] = cx;
    cart[2 * e + 1] = cy;
    m = fmaxf(fabsf(cx), fabsf(cy));
  }
#pragma unroll
  for (int s = 32; s > 0; s >>= 1)
    m = fmaxf(m, __shfl_xor(m, s, 64));
  __shared__ float wm[4];
  int lane = threadIdx.x & 63, wid = threadIdx.x >> 6;
  if (lane == 0) wm[wid] = m;
  __syncthreads();
  if (threadIdx.x == 0) {
    float mm = fmaxf(fmaxf(wm[0], wm[1]), fmaxf(wm[2], wm[3]));
    atomicMax(maxv, __float_as_uint(mm));
  }
}

// ---------------- conv2 pass A: Y[nl][k][o] (proven 0-conflict layout, r7).
// stage A v3: r7/r11 kk-outer dataflow, but TWO rows per iteration for 2x load
// ILP. Pairs (w,w+4),(w+8,w+12),(w+16,w+20) are all < 24 -> both pointers are
// unconditionally w2b (no select). xl b128 reads shared across the row pair.
// Tail rows 24 (w=0) and 25 (w=1, b2b) use the single-row loop; wave-uniform.
// Edge phase: node-grouped edges, per-nl Y column cached in 26 VGPRs (r7).
template <typename T>
__device__ void k4_impl(K4Smem& S,
    const int* __restrict__ ei, const float* __restrict__ cart, const float* __restrict__ maxv_f,
    const float* __restrict__ x2,
    const T* __restrict__ w2a, const T* __restrict__ b2a,
    const T* __restrict__ w2b, const T* __restrict__ b2b,
    const int* __restrict__ offN, const int* __restrict__ ess,
    const int* __restrict__ dpos,
    float* __restrict__ msg) {
  int tid = threadIdx.x, t = blockIdx.x;
  int n0 = t * TSN;
  if (tid < TSN * 32) S.xl[tid >> 5][tid & 31] = x2[n0 * 32 + tid];
  for (int j = tid; j < 50; j += 256) S.w2a[j] = lo(w2a, j);
  for (int j = tid; j < 25; j += 256) S.b2a[j] = lo(b2a, j);
  __syncthreads();
  int w = tid >> 6, o = tid & 63;
  // ---- stage A v3: paired rows
  {
    const float4* x0p = (const float4*)S.xl[0];
    const float4* x1p = (const float4*)S.xl[1];
    const float4* x2p = (const float4*)S.xl[2];
    const float4* x3p = (const float4*)S.xl[3];
#pragma unroll
    for (int p = 0; p < 3; ++p) {
      int ka = w + 8 * p, kb = ka + 4;          // ka<=19, kb<=23 -> both w2b
      const T* sa = w2b + ka * 2048;
      const T* sb = w2b + kb * 2048;
      float a0 = 0.f, a1 = 0.f, a2 = 0.f, a3 = 0.f;
      float b0 = 0.f, b1 = 0.f, b2 = 0.f, b3 = 0.f;
#pragma unroll
      for (int i4 = 0; i4 < 8; ++i4) {
        float qa0 = lo(sa, (i4 * 4 + 0) * 64 + o);
        float qa1 = lo(sa, (i4 * 4 + 1) * 64 + o);
        float qa2 = lo(sa, (i4 * 4 + 2) * 64 + o);
        float qa3 = lo(sa, (i4 * 4 + 3) * 64 + o);
        float qb0 = lo(sb, (i4 * 4 + 0) * 64 + o);
        float qb1 = lo(sb, (i4 * 4 + 1) * 64 + o);
        float qb2 = lo(sb, (i4 * 4 + 2) * 64 + o);
        float qb3 = lo(sb, (i4 * 4 + 3) * 64 + o);
        float4 xv0 = x0p[i4], xv1 = x1p[i4], xv2 = x2p[i4], xv3 = x3p[i4];
        a0 += xv0.x * qa0 + xv0.y * qa1 + xv0.z * qa2 + xv0.w * qa3;
        a1 += xv1.x * qa0 + xv1.y * qa1 + xv1.z * qa2 + xv1.w * qa3;
        a2 += xv2.x * qa0 + xv2.y * qa1 + xv2.z * qa2 + xv2.w * qa3;
        a3 += xv3.x * qa0 + xv3.y * qa1 + xv3.z * qa2 + xv3.w * qa3;
        b0 += xv0.x * qb0 + xv0.y * qb1 + xv0.z * qb2 + xv0.w * qb3;
        b1 += xv1.x * qb0 + xv1.y * qb1 + xv1.z * qb2 + xv1.w * qb3;
        b2 += xv2.x * qb0 + xv2.y * qb1 + xv2.z * qb2 + xv2.w * qb3;
        b3 += xv3.x * qb0 + xv3.y * qb1 + xv3.z * qb2 + xv3.w * qb3;
      }
      S.Y[0][ka][o] = a0; S.Y[1][ka][o] = a1;
      S.Y[2][ka][o] = a2; S.Y[3][ka][o] = a3;
      S.Y[0][kb][o] = b0; S.Y[1][kb][o] = b1;
      S.Y[2][kb][o] = b2; S.Y[3][kb][o] = b3;
    }
    if (w < 2) {                                 // tail: row 24 (w2b) / 25 (b2b)
      int kk = 24 + w;
      const T* srcp = (w == 0) ? (w2b + 24 * 2048) : b2b;
      float a0 = 0.f, a1 = 0.f, a2 = 0.f, a3 = 0.f;
#pragma unroll
      for (int i4 = 0; i4 < 8; ++i4) {
        float q0 = lo(srcp, (i4 * 4 + 0) * 64 + o);
        float q1 = lo(srcp, (i4 * 4 + 1) * 64 + o);
        float q2 = lo(srcp, (i4 * 4 + 2) * 64 + o);
        float q3 = lo(srcp, (i4 * 4 + 3) * 64 + o);
        float4 xv0 = x0p[i4], xv1 = x1p[i4], xv2 = x2p[i4], xv3 = x3p[i4];
        a0 += xv0.x * q0 + xv0.y * q1 + xv0.z * q2 + xv0.w * q3;
        a1 += xv1.x * q0 + xv1.y * q1 + xv1.z * q2 + xv1.w * q3;
        a2 += xv2.x * q0 + xv2.y * q1 + xv2.z * q2 + xv2.w * q3;
        a3 += xv3.x * q0 + xv3.y * q1 + xv3.z * q2 + xv3.w * q3;
      }
      S.Y[0][kk][o] = a0; S.Y[1][kk][o] = a1;
      S.Y[2][kk][o] = a2; S.Y[3][kk][o] = a3;
    }
  }
  float inv = 0.5f / maxv_f[0];
  int j0 = offN[n0], j1 = offN[n0 + TSN];
  float yreg[26];
  int cur_nl = -1;
  for (int jb = j0; jb < j1; jb += EC4) {
    int ecnt = j1 - jb; if (ecnt > EC4) ecnt = EC4;
    __syncthreads();   // Y ready (1st) / staging reuse safe (later)
    if (tid < ecnt) {
      int e = ess[jb + tid];
      int r2 = ei[e] >> 1;
      S.nll[tid] = r2 & (TSN - 1);
      S.dpl[tid] = dpos[e];
      S.axl[tid] = cart[2 * e] * inv + 0.5f;
      S.ayl[tid] = cart[2 * e + 1] * inv + 0.5f;
    }
    __syncthreads();
    for (int idx = tid; idx < ecnt * 32; idx += 256) {
      int j = idx >> 5, k = idx & 31;
      if (k < 25)
        S.tl[j][k] = fmaxf(S.axl[j] * S.w2a[k] + S.ayl[j] * S.w2a[25 + k] + S.b2a[k], 0.f);
      else
        S.tl[j][k] = (k == 25) ? 1.f : 0.f;
    }
    __syncthreads();
    // contiguous per-wave partition keeps nl runs long -> rare (wave-uniform) reloads
    int slo = (ecnt * w) >> 2;
    int shi = (ecnt * (w + 1)) >> 2;
    for (int sj = slo; sj < shi; ++sj) {
      int nl = S.nll[sj];
      if (nl != cur_nl) {
        cur_nl = nl;
#pragma unroll
        for (int k = 0; k < 26; ++k) yreg[k] = S.Y[nl][k][o];
      }
      const float4* tq = (const float4*)S.tl[sj];
      float a0 = 0.f, a1 = 0.f, a2 = 0.f, a3 = 0.f;
      float4 tv;
      tv = tq[0]; a0 += tv.x * yreg[0];  a1 += tv.y * yreg[1];  a2 += tv.z * yreg[2];  a3 += tv.w * yreg[3];
      tv = tq[1]; a0 += tv.x * yreg[4];  a1 += tv.y * yreg[5];  a2 += tv.z * yreg[6];  a3 += tv.w * yreg[7];
      tv = tq[2]; a0 += tv.x * yreg[8];  a1 += tv.y * yreg[9];  a2 += tv.z * yreg[10]; a3 += tv.w * yreg[11];
      tv = tq[3]; a0 += tv.x * yreg[12]; a1 += tv.y * yreg[13]; a2 += tv.z * yreg[14]; a3 += tv.w * yreg[15];
      tv = tq[4]; a0 += tv.x * yreg[16]; a1 += tv.y * yreg[17]; a2 += tv.z * yreg[18]; a3 += tv.w * yreg[19];
      tv = tq[5]; a0 += tv.x * yreg[20]; a1 += tv.y * yreg[21]; a2 += tv.z * yreg[22]; a3 += tv.w * yreg[23];
      tv = tq[6]; a0 += tv.x * yreg[24]; a1 += tv.y * yreg[25];   // tl[25]=1 -> bias
      msg[(size_t)S.dpl[sj] * 64 + o] = (a0 + a1) + (a2 + a3);
    }
  }
}

__global__ __launch_bounds__(256, 4) void k4_both(
    const int* __restrict__ flag,
    const int* ei, const float* cart, const float* maxv_f, const float* x2,
    const void* w2a, const void* b2a, const void* w2b, const void* b2b,
    const int* offN, const int* ess, const int* dpos, float* msg) {
  extern __shared__ char sm4[];
  K4Smem& S = *reinterpret_cast<K4Smem*>(sm4);
  if (flag[0] == 1)
    k4_impl<float>(S, ei, cart, maxv_f, x2, (const float*)w2a, (const float*)b2a,
                   (const float*)w2b, (const float*)b2b, offN, ess, dpos, msg);
  else
    k4_impl<bf16>(S, ei, cart, maxv_f, x2, (const bf16*)w2a, (const bf16*)b2a,
                  (const bf16*)w2b, (const bf16*)b2b, offN, ess, dpos, msg);
}

// ---------------- conv2 pass B + pair max-pool + graph sum (h2 never hits HBM)
template <typename T>
__device__ void k5_impl(K5Smem& S,
    const float* __restrict__ msg, const int* __restrict__ off2,
    const float* __restrict__ x2,
    const T* __restrict__ root2, const T* __restrict__ bias2,
    const int* __restrict__ batch,
    float* __restrict__ gsum, float* __restrict__ gcnt) {
  int tid = threadIdx.x;
  for (int j = tid; j < 2048; j += 256) S.r2l[j] = lo(root2, j);
  if (tid < 64) S.b2l[tid] = lo(bias2, tid);
  __syncthreads();
  int w = tid >> 6, o = tid & 63;
  int d = blockIdx.x * 4 + w;
  int j0 = off2[d], j1 = off2[d + 1];
  float s0 = 0.f, s1 = 0.f;
  int j = j0;
  for (; j + 1 < j1; j += 2) {
    s0 += msg[(size_t)j * 64 + o];
    s1 += msg[(size_t)(j + 1) * 64 + o];
  }
  if (j < j1) s0 += msg[(size_t)j * 64 + o];
  float c = fmaxf((float)(j1 - j0), 1.f);
  float r = S.b2l[o];
  const float* xr = x2 + d * 32;
#pragma unroll 8
  for (int i = 0; i < 32; ++i) r += xr[i] * S.r2l[i * 64 + o];
  S.hl[w][o] = elu((s0 + s1) / c + r);
  __syncthreads();
  if (tid < 128) {
    int p = tid >> 6, oo = tid & 63;
    float v = fmaxf(S.hl[2 * p][oo], S.hl[2 * p + 1][oo]);
    int m = blockIdx.x * 2 + p;
    int g = batch[4 * m];
    atomicAdd(gsum + g * 64 + oo, v);
    if (oo == 0) atomicAdd(gcnt + g, 1.f);
  }
}

__global__ __launch_bounds__(256) void k5_both(
    const int* __restrict__ flag,
    const float* msg, const int* off2, const float* x2,
    const void* root2, const void* bias2, const int* batch,
    float* gsum, float* gcnt) {
  extern __shared__ char sm5[];
  K5Smem& S = *reinterpret_cast<K5Smem*>(sm5);
  if (flag[0] == 1)
    k5_impl<float>(S, msg, off2, x2, (const float*)root2, (const float*)bias2, batch, gsum, gcnt);
  else
    k5_impl<bf16>(S, msg, off2, x2, (const bf16*)root2, (const bf16*)bias2, batch, gsum, gcnt);
}

// ---------------- graph mean -> fc1 -> elu -> fc2 -> log_softmax
template <typename T>
__device__ void k7_impl(const float* __restrict__ gsum, const float* __restrict__ gcnt,
                        const T* __restrict__ fc1_w, const T* __restrict__ fc1_b,
                        const T* __restrict__ fc2_w, const T* __restrict__ fc2_b,
                        T* __restrict__ out) {
  __shared__ float gv[64];
  __shared__ float h1s[128];
  __shared__ float zs[NC];
  __shared__ float lse;
  int g = blockIdx.x, tid = threadIdx.x;
  if (tid < 64) gv[tid] = gsum[g * 64 + tid] / fmaxf(gcnt[g], 1.f);
  __syncthreads();
  float a = lo(fc1_b, tid);
#pragma unroll 8
  for (int o = 0; o < 64; ++o) a += gv[o] * lo(fc1_w, o * 128 + tid);
  h1s[tid] = elu(a);
  __syncthreads();
  if (tid < NC) {
    float s = lo(fc2_b, tid);
    for (int j = 0; j < 128; ++j) s += h1s[j] * lo(fc2_w, j * NC + tid);
    zs[tid] = s;
  }
  __syncthreads();
  if (tid == 0) {
    float m = -1e30f;
    for (int c = 0; c < NC; ++c) m = fmaxf(m, zs[c]);
    float s = 0.f;
    for (int c = 0; c < NC; ++c) s += expf(zs[c] - m);
    lse = m + logf(s);
  }
  __syncthreads();
  if (tid < NC) sto(out, g * NC + tid, zs[tid] - lse);
}

__global__ __launch_bounds__(128) void k7_both(
    const int* __restrict__ flag,
    const float* gsum, const float* gcnt,
    const void* fc1_w, const void* fc1_b, const void* fc2_w, const void* fc2_b,
    void* out) {
  if (flag[0] == 1)
    k7_impl<float>(gsum, gcnt, (const float*)fc1_w, (const float*)fc1_b,
                   (const float*)fc2_w, (const float*)fc2_b, (float*)out);
  else
    k7_impl<bf16>(gsum, gcnt, (const bf16*)fc1_w, (const bf16*)fc1_b,
                  (const bf16*)fc2_w, (const bf16*)fc2_b, (bf16*)out);
}

extern "C" void kernel_launch(void* const* d_in, const int* in_sizes, int n_in,
                              void* d_out, int out_size, void* d_ws, size_t ws_size,
                              hipStream_t stream) {
  float* ws = (float*)d_ws;
  const int* flag = (const int*)(ws + FLAG_OFF);
  const int* ei = (const int*)d_in[19];
  const int* batch = (const int*)d_in[20];

  hipMemsetAsync(d_ws, 0, (size_t)ZERO_FLOATS * 4, stream);

  // histogram (+ dtype detect in extra block)
  kc_deg<<<NDEGB + 1, 256, 0, stream>>>(
      ei, d_in[0], d_in[1], (int*)(ws + FLAG_OFF),
      (int*)(ws + DEG1_OFF), (int*)(ws + DEG2_OFF), (int*)(ws + DEGN_OFF));
  ks_scanA<<<SC_CT, 256, 0, stream>>>(
      (const int*)(ws + DEG1_OFF), (const int*)(ws + DEGN_OFF), (const int*)(ws + DEG2_OFF),
      (int*)(ws + OFF1_OFF), (int*)(ws + OFFN_OFF), (int*)(ws + OFF2_OFF),
      (int*)(ws + BSUM_OFF));
  ks_scanB<<<3, 256, 0, stream>>>((int*)(ws + BSUM_OFF));
  ks_scanC<<<SC_CT, 256, 0, stream>>>(
      (int*)(ws + OFF1_OFF), (int*)(ws + OFFN_OFF), (int*)(ws + OFF2_OFF),
      (int*)(ws + CUR1_OFF), (int*)(ws + CURN_OFF), (int*)(ws + CUR2_OFF),
      (const int*)(ws + BSUM_OFF));
  kc_place<<<NDEGB, 256, 0, stream>>>(
      ei, (int*)(ws + CUR1_OFF), (int*)(ws + ES1_OFF),
      (int*)(ws + CUR2_OFF), (int*)(ws + DPOS_OFF),
      (int*)(ws + CURN_OFF), (int*)(ws + ESS_OFF));

  // conv1 + pool1 (single launch, runtime dtype branch)
  k1_both<<<NBLK1, 256, sizeof(K1Smem), stream>>>(
      flag, d_in[0], d_in[1], d_in[2], ei,
      d_in[3], d_in[4], d_in[5], d_in[6], d_in[7], d_in[8],
      (const int*)(ws + OFF1_OFF), (const int*)(ws + ES1_OFF),
      ws + X2_OFF, ws + P2_OFF);

  // cart/maxv (dtype-free)
  k3_cart<<<NDEGB, 256, 0, stream>>>(
      ei, ws + P2_OFF, ws + CT_OFF, (unsigned int*)(ws + MV_OFF));

  // conv2 pass A (factorized messages; single launch, runtime dtype branch)
  k4_both<<<NTS, 256, sizeof(K4Smem), stream>>>(
      flag, ei, ws + CT_OFF, ws + MV_OFF, ws + X2_OFF,
      d_in[9], d_in[10], d_in[11], d_in[12],
      (const int*)(ws + OFFN_OFF), (const int*)(ws + ESS_OFF),
      (const int*)(ws + DPOS_OFF), ws + MSG_OFF);

  // conv2 pass B + pool2 + graph segment-sum (fused)
  k5_both<<<N2 / 4, 256, sizeof(K5Smem), stream>>>(
      flag, ws + MSG_OFF, (const int*)(ws + OFF2_OFF), ws + X2_OFF,
      d_in[13], d_in[14], batch, ws + GS_OFF, ws + GC_OFF);

  // head
  k7_both<<<NGRAPH, 128, 0, stream>>>(
      flag, ws + GS_OFF, ws + GC_OFF,
      d_in[15], d_in[16], d_in[17], d_in[18], d_out);
}

// Round 13
// 254.332 us; speedup vs baseline: 1.5833x; 1.5833x over previous
//
#include <hip/hip_runtime.h>
#include <hip/hip_bf16.h>

#define N_NODES 30000
#define N_EDGES 120000
#define NGRAPH  512
#define N2      15000
#define N3      7500
#define NC      10

#define TSN   4                 // src pooled-nodes per tile in k4
#define NTS   (N2 / TSN)        // 3750
#define EC4   64                // edge chunk, k4
#define NB1   32                // original nodes per block, k1
#define NBLK1 ((N_NODES + NB1 - 1) / NB1)   // 938
#define EC1   256               // edge chunk, k1
#define NDEGB ((N_EDGES + 255) / 256)       // 469
#define NP2B  ((N2 + 255) / 256)            // 59

// scan chunking: deg1(30000), degN(15000), deg2(15000)
#define SC_C1 118
#define SC_CN 59
#define SC_C2 59
#define SC_CT (SC_C1 + SC_CN + SC_C2)   // 236

typedef __hip_bfloat16 bf16;

__device__ __forceinline__ float lo(const float* p, int i) { return p[i]; }
__device__ __forceinline__ float lo(const bf16* p, int i) { return __bfloat162float(p[i]); }
__device__ __forceinline__ void sto(float* p, int i, float v) { p[i] = v; }
__device__ __forceinline__ void sto(bf16* p, int i, float v) { p[i] = __float2bfloat16(v); }
__device__ __forceinline__ float elu(float x) { return x > 0.f ? x : expm1f(x); }
template <typename T> __host__ __device__ constexpr int want_flag() { return sizeof(T) == 4 ? 1 : 0; }

// ---------------- workspace layout (4-byte units) ----------------
// zero region (memset each call):
#define MV_OFF    0         // maxv (uint bits): 1
#define GS_OFF    1         // gsum: 512*64 = 32768
#define GC_OFF    32769     // gcnt: 512
#define DEG1_OFF  33281     // in-degree per node (int): 30000
#define DEG2_OFF  63281     // valid in-degree per pooled node (int): 15000
#define DEGN_OFF  78281     // valid out-degree per pooled SRC node (int): 15000
#define ZERO_FLOATS 93281
// non-zero region:
#define OFF1_OFF  93281     // conv1 CSR offsets (int): 30001
#define CUR1_OFF  123282    // 30000
#define OFF2_OFF  153282    // conv2 dest CSR offsets (int): 15001
#define CUR2_OFF  168283    // 15000
#define OFFN_OFF  183283    // conv2 src-node CSR offsets (int): 15001
#define CURN_OFF  198284    // 15000
#define BSUM_OFF  213284    // scan chunk sums (int): 236
#define ES1_OFF   213520    // conv1 dest-sorted edge ids (int): 120000
#define ESS_OFF   333520    // conv2 src-node-sorted edge ids (int): 120000
#define DPOS_OFF  453520    // edge -> dest-sorted row (int): 120000
#define X2_OFF    573520    // x2: N2*32 = 480000
#define P2_OFF    1053520   // pos2: N2*2 = 30000
#define CT_OFF    1083520   // cart: E*2 = 240000
#define MSG_OFF   1323520   // message buffer: E*64 = 7680000
#define FLAG_OFF  9003520   // dtype flag (int)
// total = 9003521 floats ~= 36 MB

// ---------------- shared-memory layouts
struct K1Smem {
  float srow[NB1][28];
  float axl[EC1], ayl[EC1], xsl[EC1];
  float w1a[50];
  float b1a[25];
  float b1b[32];
  float r1[32];
  float bs1[32];
  float hbuf[NB1][33];
  int offl[NB1 + 1];
};  // ~12 KB

struct K5Smem {
  float r2l[2048];
  float b2l[64];
  float hl[4][64];
};  // ~9.5 KB

// ---------------- degree histograms + dtype detect (fused; dtype-free)
__global__ __launch_bounds__(256) void kc_deg(
    const int* __restrict__ ei, const void* x, const void* ea, int* __restrict__ flag,
    int* __restrict__ deg1, int* __restrict__ deg2, int* __restrict__ degN) {
  if (blockIdx.x == NDEGB) {
    const bf16* xb = (const bf16*)x;
    const bf16* eb = (const bf16*)ea;
    int tid = threadIdx.x;
    float a = __bfloat162float(xb[tid]);
    float b = __bfloat162float(eb[tid]);
    int bad = (!(fabsf(a) < 1e3f)) || (!(fabsf(b) < 1e3f));
    unsigned long long m = __ballot(bad);
    __shared__ int anyb[4];
    int w = tid >> 6;
    if ((tid & 63) == 0) anyb[w] = (m != 0ULL) ? 1 : 0;
    __syncthreads();
    if (tid == 0) flag[0] = (anyb[0] | anyb[1] | anyb[2] | anyb[3]);
    return;
  }
  int e = blockIdx.x * 256 + threadIdx.x;
  if (e >= N_EDGES) return;
  int row = ei[e], col = ei[N_EDGES + e];
  atomicAdd(deg1 + col, 1);
  int r2 = row >> 1, c2 = col >> 1;
  if (r2 != c2) {
    atomicAdd(deg2 + c2, 1);
    atomicAdd(degN + r2, 1);
  }
}

// ---------------- hierarchical exclusive scan over the three deg arrays
__global__ __launch_bounds__(256) void ks_scanA(
    const int* __restrict__ deg1, const int* __restrict__ degN, const int* __restrict__ deg2,
    int* __restrict__ off1, int* __restrict__ offN, int* __restrict__ off2,
    int* __restrict__ bsum) {
  __shared__ int buf[256];
  int c = blockIdx.x, tid = threadIdx.x;
  const int* deg; int* off; int n, local;
  if (c < SC_C1)              { deg = deg1; off = off1; n = 30000; local = c; }
  else if (c < SC_C1 + SC_CN) { deg = degN; off = offN; n = 15000; local = c - SC_C1; }
  else                        { deg = deg2; off = off2; n = 15000; local = c - SC_C1 - SC_CN; }
  int i = local * 256 + tid;
  int v = (i < n) ? deg[i] : 0;
  buf[tid] = v;
  __syncthreads();
  for (int s = 1; s < 256; s <<= 1) {
    int t = (tid >= s) ? buf[tid - s] : 0;
    __syncthreads();
    buf[tid] += t;
    __syncthreads();
  }
  if (i <= n) off[i] = buf[tid] - v;
  if (tid == 255) bsum[c] = buf[255];
}

// scanB: blocks 0..2 scan bsum chunks; blocks 3.. compute pos2 (dtype via flag).
__global__ __launch_bounds__(256) void ks_scanB(
    int* __restrict__ bsum, const int* __restrict__ flag,
    const void* __restrict__ pos, float* __restrict__ pos2) {
  int a = blockIdx.x, tid = threadIdx.x;
  if (a >= 3) {
    int m = (a - 3) * 256 + tid;
    if (m < N2) {
      float p0, p1, p2v, p3;
      if (flag[0] == 1) {
        const float* p = (const float*)pos;
        p0 = p[4 * m]; p1 = p[4 * m + 1]; p2v = p[4 * m + 2]; p3 = p[4 * m + 3];
      } else {
        const bf16* p = (const bf16*)pos;
        p0 = __bfloat162float(p[4 * m]);     p1 = __bfloat162float(p[4 * m + 1]);
        p2v = __bfloat162float(p[4 * m + 2]); p3 = __bfloat162float(p[4 * m + 3]);
      }
      pos2[2 * m] = 0.5f * (p0 + p2v);
      pos2[2 * m + 1] = 0.5f * (p1 + p3);
    }
    return;
  }
  __shared__ int buf[256];
  int nc, cb;
  if (a == 0)      { nc = SC_C1; cb = 0; }
  else if (a == 1) { nc = SC_CN; cb = SC_C1; }
  else             { nc = SC_C2; cb = SC_C1 + SC_CN; }
  int v = (tid < nc) ? bsum[cb + tid] : 0;
  buf[tid] = v;
  __syncthreads();
  for (int s = 1; s < 256; s <<= 1) {
    int t = (tid >= s) ? buf[tid - s] : 0;
    __syncthreads();
    buf[tid] += t;
    __syncthreads();
  }
  if (tid < nc) bsum[cb + tid] = buf[tid] - v;
}

__global__ __launch_bounds__(256) void ks_scanC(
    int* __restrict__ off1, int* __restrict__ offN, int* __restrict__ off2,
    int* __restrict__ cur1, int* __restrict__ curN, int* __restrict__ cur2,
    const int* __restrict__ bsum) {
  int c = blockIdx.x, tid = threadIdx.x;
  int* off; int* cur; int n, local;
  if (c < SC_C1)              { off = off1; cur = cur1; n = 30000; local = c; }
  else if (c < SC_C1 + SC_CN) { off = offN; cur = curN; n = 15000; local = c - SC_C1; }
  else                        { off = off2; cur = cur2; n = 15000; local = c - SC_C1 - SC_CN; }
  int add = bsum[c];
  int i = local * 256 + tid;
  if (i <= n) off[i] += add;
  if (i < n) cur[i] = off[i];
}

// ---------------- edge placement + cart + maxv (fused; pos2 ready from scanB)
__global__ __launch_bounds__(256) void kc_place(
    const int* __restrict__ ei,
    int* __restrict__ cur1, int* __restrict__ es1,
    int* __restrict__ cur2, int* __restrict__ dpos,
    int* __restrict__ curN, int* __restrict__ ess,
    const float* __restrict__ pos2, float* __restrict__ cart,
    unsigned int* __restrict__ maxv) {
  int e = blockIdx.x * 256 + threadIdx.x;
  float mloc = 0.f;
  if (e < N_EDGES) {
    int row = ei[e], col = ei[N_EDGES + e];
    int p = atomicAdd(cur1 + col, 1);
    es1[p] = e;
    int r2 = row >> 1, c2 = col >> 1;
    if (r2 != c2) {
      int q = atomicAdd(cur2 + c2, 1);
      dpos[e] = q;
      int u = atomicAdd(curN + r2, 1);   // src-NODE grouped -> nl runs contiguous
      ess[u] = e;
      float cx = pos2[2 * c2] - pos2[2 * r2];
      float cy = pos2[2 * c2 + 1] - pos2[2 * r2 + 1];
      cart[2 * e] = cx;
      cart[2 * e + 1] = cy;
      mloc = fmaxf(fabsf(cx), fabsf(cy));
    }
  }
#pragma unroll
  for (int s = 32; s > 0; s >>= 1)
    mloc = fmaxf(mloc, __shfl_xor(mloc, s, 64));
  __shared__ float wm[4];
  int lane = threadIdx.x & 63, wid = threadIdx.x >> 6;
  if (lane == 0) wm[wid] = mloc;
  __syncthreads();
  if (threadIdx.x == 0) {
    float mm = fmaxf(fmaxf(wm[0], wm[1]), fmaxf(wm[2], wm[3]));
    atomicMax(maxv, __float_as_uint(mm));
  }
}

// ---------------- conv1: dest-side S factorization (f_in=1 -> S is 26 floats/node)
template <typename T>
__device__ void k1_impl(K1Smem& S,
    const T* __restrict__ x, const T* __restrict__ ea,
    const int* __restrict__ ei,
    const T* __restrict__ w1a, const T* __restrict__ b1a,
    const T* __restrict__ w1b, const T* __restrict__ b1b,
    const T* __restrict__ root1, const T* __restrict__ bias1,
    const int* __restrict__ off1, const int* __restrict__ es1,
    float* __restrict__ x2) {
  int tid = threadIdx.x, t = blockIdx.x;
  int n0 = t * NB1;
  for (int j = tid; j < 50; j += 256) S.w1a[j] = lo(w1a, j);
  for (int j = tid; j < 25; j += 256) S.b1a[j] = lo(b1a, j);
  if (tid < 32) {
    S.b1b[tid] = lo(b1b, tid);
    S.r1[tid] = lo(root1, tid);
    S.bs1[tid] = lo(bias1, tid);
  }
  if (tid <= NB1) {
    int n = n0 + tid; if (n > N_NODES) n = N_NODES;
    S.offl[tid] = off1[n];
  }
  int half = tid >> 5, lk = tid & 31;
  float wreg[28];
#pragma unroll
  for (int k = 0; k < 25; ++k) wreg[k] = lo(w1b, k * 32 + lk);
  wreg[26] = 0.f; wreg[27] = 0.f;
  __syncthreads();
  wreg[25] = S.b1b[lk];
  float wa0 = 0.f, wa1 = 0.f, wb = 0.f;
  if (lk < 25) { wa0 = S.w1a[lk]; wa1 = S.w1a[25 + lk]; wb = S.b1a[lk]; }
  int jbeg = S.offl[0], jend = S.offl[NB1];
  int base = half * 4;
  float s0 = 0.f, s1 = 0.f, s2 = 0.f, s3 = 0.f;
  for (int jb = jbeg; jb < jend; jb += EC1) {
    int ecnt = jend - jb; if (ecnt > EC1) ecnt = EC1;
    __syncthreads();
    if (tid < ecnt) {
      int e = es1[jb + tid];
      S.axl[tid] = lo(ea, 2 * e);
      S.ayl[tid] = lo(ea, 2 * e + 1);
      S.xsl[tid] = lo(x, ei[e]);
    }
    __syncthreads();
    int je = jb + ecnt;
#define K1ACC(i, sacc) { \
    int lj = S.offl[base + i]; if (lj < jb) lj = jb; \
    int hj = S.offl[base + i + 1]; if (hj > je) hj = je; \
    for (int j = lj; j < hj; ++j) { \
      int sj = j - jb; \
      float tk = (lk < 25) ? fmaxf(S.axl[sj] * wa0 + S.ayl[sj] * wa1 + wb, 0.f) : 1.f; \
      sacc += S.xsl[sj] * tk; } }
    K1ACC(0, s0) K1ACC(1, s1) K1ACC(2, s2) K1ACC(3, s3)
#undef K1ACC
  }
  if (lk < 26) {
    S.srow[base][lk] = s0; S.srow[base + 1][lk] = s1;
    S.srow[base + 2][lk] = s2; S.srow[base + 3][lk] = s3;
  } else if (lk < 28) {
    S.srow[base][lk] = 0.f; S.srow[base + 1][lk] = 0.f;
    S.srow[base + 2][lk] = 0.f; S.srow[base + 3][lk] = 0.f;
  }
#pragma unroll
  for (int i = 0; i < 4; ++i) {
    int nl = base + i, n = n0 + nl;
    if (n < N_NODES) {
      const float4* sq = (const float4*)S.srow[nl];
      float a0 = 0.f, a1 = 0.f, a2 = 0.f, a3 = 0.f;
#pragma unroll
      for (int q = 0; q < 7; ++q) {
        float4 sv = sq[q];
        a0 += sv.x * wreg[4 * q];     a1 += sv.y * wreg[4 * q + 1];
        a2 += sv.z * wreg[4 * q + 2]; a3 += sv.w * wreg[4 * q + 3];
      }
      float c = (float)(S.offl[nl + 1] - S.offl[nl]);
      c = fmaxf(c, 1.f);
      S.hbuf[nl][lk] = elu(((a0 + a1) + (a2 + a3)) / c + lo(x, n) * S.r1[lk] + S.bs1[lk]);
    }
  }
  __syncthreads();
  for (int idx = tid; idx < (NB1 / 2) * 32; idx += 256) {
    int pl = idx >> 5, oo = idx & 31;
    int m = t * (NB1 / 2) + pl;
    if (m < N2)
      x2[m * 32 + oo] = fmaxf(S.hbuf[2 * pl][oo], S.hbuf[2 * pl + 1][oo]);
  }
}

__global__ __launch_bounds__(256, 4) void k1_both(
    const int* __restrict__ flag,
    const void* x, const void* ea, const int* ei,
    const void* w1a, const void* b1a, const void* w1b, const void* b1b,
    const void* root1, const void* bias1,
    const int* off1, const int* es1, float* x2) {
  extern __shared__ char sm1[];
  K1Smem& S = *reinterpret_cast<K1Smem*>(sm1);
  if (flag[0] == 1)
    k1_impl<float>(S, (const float*)x, (const float*)ea, ei,
                   (const float*)w1a, (const float*)b1a, (const float*)w1b, (const float*)b1b,
                   (const float*)root1, (const float*)bias1, off1, es1, x2);
  else
    k1_impl<bf16>(S, (const bf16*)x, (const bf16*)ea, ei,
                  (const bf16*)w1a, (const bf16*)b1a, (const bf16*)w1b, (const bf16*)b1b,
                  (const bf16*)root1, (const bf16*)bias1, off1, es1, x2);
}

// ---------------- conv2 pass A: EXACT r7 kernel (proven 75 us; VGPR 52).
// Y[nl][k][o] 0-conflict layout; scalar kk-outer stage A; node-grouped edges
// with per-nl Y column cached in 26 VGPRs (wave-uniform reload).
template <typename T>
__global__ __launch_bounds__(256, 4) void k4_src(
    const int* __restrict__ flag,
    const int* __restrict__ ei, const float* __restrict__ cart, const float* __restrict__ maxv_f,
    const float* __restrict__ x2,
    const T* __restrict__ w2a, const T* __restrict__ b2a,
    const T* __restrict__ w2b, const T* __restrict__ b2b,
    const int* __restrict__ offN, const int* __restrict__ ess,
    const int* __restrict__ dpos,
    float* __restrict__ msg) {
  if (flag[0] != want_flag<T>()) return;
  __shared__ float Y[TSN][26][64];             // 26.6 KB, writes+reads conflict-free
  __shared__ __align__(16) float tl[EC4][32];  // 8 KB; rows b128-able; t[25]=1, 26..31=0
  __shared__ float xl[TSN][32];
  __shared__ float w2a_l[50];
  __shared__ float b2a_l[25];
  __shared__ float axl[EC4], ayl[EC4];
  __shared__ int dpl[EC4], nll[EC4];
  int tid = threadIdx.x, t = blockIdx.x;
  int n0 = t * TSN;
  if (tid < TSN * 32) xl[tid >> 5][tid & 31] = x2[n0 * 32 + tid];
  for (int j = tid; j < 50; j += 256) w2a_l[j] = lo(w2a, j);
  for (int j = tid; j < 25; j += 256) b2a_l[j] = lo(b2a, j);
  __syncthreads();
  int w = tid >> 6, o = tid & 63;
  // stage A: Y[nl][kk][o]; kk=25 from b2b (bias row)
  for (int kk = w; kk < 26; kk += 4) {
    const T* srcp = (kk < 25) ? (w2b + kk * 2048) : b2b;
    float a0 = 0.f, a1 = 0.f, a2 = 0.f, a3 = 0.f;
#pragma unroll 8
    for (int i = 0; i < 32; ++i) {
      float q = lo(srcp, i * 64 + o);
      a0 += xl[0][i] * q;
      a1 += xl[1][i] * q;
      a2 += xl[2][i] * q;
      a3 += xl[3][i] * q;
    }
    Y[0][kk][o] = a0; Y[1][kk][o] = a1; Y[2][kk][o] = a2; Y[3][kk][o] = a3;
  }
  float inv = 0.5f / maxv_f[0];
  int j0 = offN[n0], j1 = offN[n0 + TSN];
  float yreg[26];
  int cur_nl = -1;
  for (int jb = j0; jb < j1; jb += EC4) {
    int ecnt = j1 - jb; if (ecnt > EC4) ecnt = EC4;
    __syncthreads();   // Y ready (1st) / staging reuse safe (later)
    if (tid < ecnt) {
      int e = ess[jb + tid];
      int r2 = ei[e] >> 1;
      nll[tid] = r2 & (TSN - 1);
      dpl[tid] = dpos[e];
      axl[tid] = cart[2 * e] * inv + 0.5f;
      ayl[tid] = cart[2 * e + 1] * inv + 0.5f;
    }
    __syncthreads();
    for (int idx = tid; idx < ecnt * 32; idx += 256) {
      int j = idx >> 5, k = idx & 31;
      if (k < 25)
        tl[j][k] = fmaxf(axl[j] * w2a_l[k] + ayl[j] * w2a_l[25 + k] + b2a_l[k], 0.f);
      else
        tl[j][k] = (k == 25) ? 1.f : 0.f;
    }
    __syncthreads();
    int slo = (ecnt * w) >> 2;
    int shi = (ecnt * (w + 1)) >> 2;
    for (int sj = slo; sj < shi; ++sj) {
      int nl = nll[sj];
      if (nl != cur_nl) {
        cur_nl = nl;
#pragma unroll
        for (int k = 0; k < 26; ++k) yreg[k] = Y[nl][k][o];
      }
      const float4* tq = (const float4*)tl[sj];
      float a0 = 0.f, a1 = 0.f, a2 = 0.f, a3 = 0.f;
      float4 tv;
      tv = tq[0]; a0 += tv.x * yreg[0];  a1 += tv.y * yreg[1];  a2 += tv.z * yreg[2];  a3 += tv.w * yreg[3];
      tv = tq[1]; a0 += tv.x * yreg[4];  a1 += tv.y * yreg[5];  a2 += tv.z * yreg[6];  a3 += tv.w * yreg[7];
      tv = tq[2]; a0 += tv.x * yreg[8];  a1 += tv.y * yreg[9];  a2 += tv.z * yreg[10]; a3 += tv.w * yreg[11];
      tv = tq[3]; a0 += tv.x * yreg[12]; a1 += tv.y * yreg[13]; a2 += tv.z * yreg[14]; a3 += tv.w * yreg[15];
      tv = tq[4]; a0 += tv.x * yreg[16]; a1 += tv.y * yreg[17]; a2 += tv.z * yreg[18]; a3 += tv.w * yreg[19];
      tv = tq[5]; a0 += tv.x * yreg[20]; a1 += tv.y * yreg[21]; a2 += tv.z * yreg[22]; a3 += tv.w * yreg[23];
      tv = tq[6]; a0 += tv.x * yreg[24]; a1 += tv.y * yreg[25];   // tl[25]=1 -> bias
      msg[(size_t)dpl[sj] * 64 + o] = (a0 + a1) + (a2 + a3);
    }
  }
}

// ---------------- conv2 pass B + pair max-pool + graph sum (h2 never hits HBM)
template <typename T>
__device__ void k5_impl(K5Smem& S,
    const float* __restrict__ msg, const int* __restrict__ off2,
    const float* __restrict__ x2,
    const T* __restrict__ root2, const T* __restrict__ bias2,
    const int* __restrict__ batch,
    float* __restrict__ gsum, float* __restrict__ gcnt) {
  int tid = threadIdx.x;
  for (int j = tid; j < 2048; j += 256) S.r2l[j] = lo(root2, j);
  if (tid < 64) S.b2l[tid] = lo(bias2, tid);
  __syncthreads();
  int w = tid >> 6, o = tid & 63;
  int d = blockIdx.x * 4 + w;
  int j0 = off2[d], j1 = off2[d + 1];
  float s0 = 0.f, s1 = 0.f;
  int j = j0;
  for (; j + 1 < j1; j += 2) {
    s0 += msg[(size_t)j * 64 + o];
    s1 += msg[(size_t)(j + 1) * 64 + o];
  }
  if (j < j1) s0 += msg[(size_t)j * 64 + o];
  float c = fmaxf((float)(j1 - j0), 1.f);
  float r = S.b2l[o];
  const float* xr = x2 + d * 32;
#pragma unroll 8
  for (int i = 0; i < 32; ++i) r += xr[i] * S.r2l[i * 64 + o];
  S.hl[w][o] = elu((s0 + s1) / c + r);
  __syncthreads();
  if (tid < 128) {
    int p = tid >> 6, oo = tid & 63;
    float v = fmaxf(S.hl[2 * p][oo], S.hl[2 * p + 1][oo]);
    int m = blockIdx.x * 2 + p;
    int g = batch[4 * m];
    atomicAdd(gsum + g * 64 + oo, v);
    if (oo == 0) atomicAdd(gcnt + g, 1.f);
  }
}

__global__ __launch_bounds__(256) void k5_both(
    const int* __restrict__ flag,
    const float* msg, const int* off2, const float* x2,
    const void* root2, const void* bias2, const int* batch,
    float* gsum, float* gcnt) {
  extern __shared__ char sm5[];
  K5Smem& S = *reinterpret_cast<K5Smem*>(sm5);
  if (flag[0] == 1)
    k5_impl<float>(S, msg, off2, x2, (const float*)root2, (const float*)bias2, batch, gsum, gcnt);
  else
    k5_impl<bf16>(S, msg, off2, x2, (const bf16*)root2, (const bf16*)bias2, batch, gsum, gcnt);
}

// ---------------- graph mean -> fc1 -> elu -> fc2 -> log_softmax
template <typename T>
__device__ void k7_impl(const float* __restrict__ gsum, const float* __restrict__ gcnt,
                        const T* __restrict__ fc1_w, const T* __restrict__ fc1_b,
                        const T* __restrict__ fc2_w, const T* __restrict__ fc2_b,
                        T* __restrict__ out) {
  __shared__ float gv[64];
  __shared__ float h1s[128];
  __shared__ float zs[NC];
  __shared__ float lse;
  int g = blockIdx.x, tid = threadIdx.x;
  if (tid < 64) gv[tid] = gsum[g * 64 + tid] / fmaxf(gcnt[g], 1.f);
  __syncthreads();
  float a = lo(fc1_b, tid);
#pragma unroll 8
  for (int o = 0; o < 64; ++o) a += gv[o] * lo(fc1_w, o * 128 + tid);
  h1s[tid] = elu(a);
  __syncthreads();
  if (tid < NC) {
    float s = lo(fc2_b, tid);
    for (int j = 0; j < 128; ++j) s += h1s[j] * lo(fc2_w, j * NC + tid);
    zs[tid] = s;
  }
  __syncthreads();
  if (tid == 0) {
    float m = -1e30f;
    for (int c = 0; c < NC; ++c) m = fmaxf(m, zs[c]);
    float s = 0.f;
    for (int c = 0; c < NC; ++c) s += expf(zs[c] - m);
    lse = m + logf(s);
  }
  __syncthreads();
  if (tid < NC) sto(out, g * NC + tid, zs[tid] - lse);
}

__global__ __launch_bounds__(128) void k7_both(
    const int* __restrict__ flag,
    const float* gsum, const float* gcnt,
    const void* fc1_w, const void* fc1_b, const void* fc2_w, const void* fc2_b,
    void* out) {
  if (flag[0] == 1)
    k7_impl<float>(gsum, gcnt, (const float*)fc1_w, (const float*)fc1_b,
                   (const float*)fc2_w, (const float*)fc2_b, (float*)out);
  else
    k7_impl<bf16>(gsum, gcnt, (const bf16*)fc1_w, (const bf16*)fc1_b,
                  (const bf16*)fc2_w, (const bf16*)fc2_b, (bf16*)out);
}

extern "C" void kernel_launch(void* const* d_in, const int* in_sizes, int n_in,
                              void* d_out, int out_size, void* d_ws, size_t ws_size,
                              hipStream_t stream) {
  float* ws = (float*)d_ws;
  const int* flag = (const int*)(ws + FLAG_OFF);
  const int* ei = (const int*)d_in[19];
  const int* batch = (const int*)d_in[20];

  hipMemsetAsync(d_ws, 0, (size_t)ZERO_FLOATS * 4, stream);

  // histogram (+ dtype detect in extra block)
  kc_deg<<<NDEGB + 1, 256, 0, stream>>>(
      ei, d_in[0], d_in[1], (int*)(ws + FLAG_OFF),
      (int*)(ws + DEG1_OFF), (int*)(ws + DEG2_OFF), (int*)(ws + DEGN_OFF));
  ks_scanA<<<SC_CT, 256, 0, stream>>>(
      (const int*)(ws + DEG1_OFF), (const int*)(ws + DEGN_OFF), (const int*)(ws + DEG2_OFF),
      (int*)(ws + OFF1_OFF), (int*)(ws + OFFN_OFF), (int*)(ws + OFF2_OFF),
      (int*)(ws + BSUM_OFF));
  // scanB + pos2 (pos2 depends only on pos; flag written by kc_deg)
  ks_scanB<<<3 + NP2B, 256, 0, stream>>>(
      (int*)(ws + BSUM_OFF), flag, d_in[2], ws + P2_OFF);
  ks_scanC<<<SC_CT, 256, 0, stream>>>(
      (int*)(ws + OFF1_OFF), (int*)(ws + OFFN_OFF), (int*)(ws + OFF2_OFF),
      (int*)(ws + CUR1_OFF), (int*)(ws + CURN_OFF), (int*)(ws + CUR2_OFF),
      (const int*)(ws + BSUM_OFF));
  // placement + cart + maxv (fused; replaces k3)
  kc_place<<<NDEGB, 256, 0, stream>>>(
      ei, (int*)(ws + CUR1_OFF), (int*)(ws + ES1_OFF),
      (int*)(ws + CUR2_OFF), (int*)(ws + DPOS_OFF),
      (int*)(ws + CURN_OFF), (int*)(ws + ESS_OFF),
      ws + P2_OFF, ws + CT_OFF, (unsigned int*)(ws + MV_OFF));

  // conv1 + pool1 (single launch, runtime dtype branch)
  k1_both<<<NBLK1, 256, sizeof(K1Smem), stream>>>(
      flag, d_in[0], d_in[1], ei,
      d_in[3], d_in[4], d_in[5], d_in[6], d_in[7], d_in[8],
      (const int*)(ws + OFF1_OFF), (const int*)(ws + ES1_OFF),
      ws + X2_OFF);

  // conv2 pass A (r7-exact; template kernels, non-matching early-returns)
  k4_src<float><<<NTS, 256, 0, stream>>>(
      flag, ei, ws + CT_OFF, ws + MV_OFF, ws + X2_OFF,
      (const float*)d_in[9], (const float*)d_in[10], (const float*)d_in[11], (const float*)d_in[12],
      (const int*)(ws + OFFN_OFF), (const int*)(ws + ESS_OFF),
      (const int*)(ws + DPOS_OFF), ws + MSG_OFF);
  k4_src<bf16><<<NTS, 256, 0, stream>>>(
      flag, ei, ws + CT_OFF, ws + MV_OFF, ws + X2_OFF,
      (const bf16*)d_in[9], (const bf16*)d_in[10], (const bf16*)d_in[11], (const bf16*)d_in[12],
      (const int*)(ws + OFFN_OFF), (const int*)(ws + ESS_OFF),
      (const int*)(ws + DPOS_OFF), ws + MSG_OFF);

  // conv2 pass B + pool2 + graph segment-sum (fused)
  k5_both<<<N2 / 4, 256, sizeof(K5Smem), stream>>>(
      flag, ws + MSG_OFF, (const int*)(ws + OFF2_OFF), ws + X2_OFF,
      d_in[13], d_in[14], batch, ws + GS_OFF, ws + GC_OFF);

  // head
  k7_both<<<NGRAPH, 128, 0, stream>>>(
      flag, ws + GS_OFF, ws + GC_OFF,
      d_in[15], d_in[16], d_in[17], d_in[18], d_out);
}